// Round 3
// baseline (355.750 us; speedup 1.0000x reference)
//
#include <hip/hip_runtime.h>
#include <hip/hip_bf16.h>
#include <stdint.h>

#define DIM 256
#define GRID_G 5
#define KTOT 2560                 // 256 * 5 * 2
#define BM 128
#define BN 256
#define BK 64
#define NTHREADS 512
#define NCHUNK (KTOT / BK)        // 40
#define AS_SH (BM * BK)           // 8192 shorts = 16 KB per buffer

typedef float f32x4 __attribute__((ext_vector_type(4)));
typedef short bf16x8 __attribute__((ext_vector_type(8)));

static __device__ __forceinline__ uint32_t f2bf_bits(float v) {
    uint32_t u = __float_as_uint(v);
    return (u + 0x7FFFu + ((u >> 16) & 1u)) >> 16;
}

// ---- W pre-transform: Wb[o][k] bf16, k = g*512 + 2*d + s ----
// source fourier_weight layout: [s][o][d][g], flat ((s*256+o)*256+d)*5+g
// each thread produces 8 consecutive k (one 16B store)
__global__ void wtransform(const float* __restrict__ W, uint16_t* __restrict__ Wb) {
    int t = blockIdx.x * blockDim.x + threadIdx.x;
    if (t >= DIM * KTOT / 8) return;
    int o  = t / (KTOT / 8);            // /320
    int k8 = t - o * (KTOT / 8);
    int k0 = k8 * 8;
    int g  = k0 >> 9;
    int r  = k0 & 511;                  // even
    int d0 = r >> 1;
    union { uint16_t v[8]; uint4 q; } u;
#pragma unroll
    for (int j = 0; j < 8; ++j) {
        int d = d0 + (j >> 1);
        int s = j & 1;
        float w = W[(((s * DIM + o) * DIM + d) * GRID_G) + g];
        u.v[j] = (uint16_t)f2bf_bits(w);
    }
    *(uint4*)((char*)Wb + (size_t)t * 16) = u.q;
}

// ---- fused feature+GEMM: BM=128 x BN=256, A-only LDS dbuf, B global->reg ----
__global__ __launch_bounds__(NTHREADS, 4)
void fourier_gemm(const float* __restrict__ x, const uint16_t* __restrict__ Wb,
                  const float* __restrict__ bias, float* __restrict__ out) {
    __shared__ __align__(16) short As[2 * AS_SH];   // 32 KB total

    const int tid  = threadIdx.x;
    const int lane = tid & 63;
    const int wave = tid >> 6;
    const int wrow = wave >> 2;     // 0..1 (64-row halves)
    const int wcol = wave & 3;      // 0..3 (64-col quarters)
    const int row0 = blockIdx.x * BM;
    const int q16  = (lane >> 4) << 4;

    f32x4 acc[4][4];
#pragma unroll
    for (int m = 0; m < 4; ++m)
#pragma unroll
        for (int n = 0; n < 4; ++n)
            acc[m][n] = (f32x4){0.f, 0.f, 0.f, 0.f};

    const int sd2 = tid & 15;       // d-pair index within 32-d slab
    const int sn  = tid >> 4;       // 0..31 (row base; rows n = sn + i*32)

    float2 xq[4];                   // this dr-group's x slice (8 elements)

#define LOAD_X(dr_)                                                           \
    {                                                                         \
        _Pragma("unroll")                                                     \
        for (int i = 0; i < 4; ++i) {                                         \
            int n = sn + i * 32;                                              \
            xq[i] = *(const float2*)&x[(size_t)(row0 + n) * DIM +             \
                                       (dr_) * 32 + 2 * sd2];                 \
        }                                                                     \
    }

#define TRIG_WRITE(kg1, buf)                                                  \
    {                                                                         \
        float kgrev = (float)(kg1) * 0.15915494309189535f;                    \
        char* abase = (char*)(As + (buf) * AS_SH);                            \
        _Pragma("unroll")                                                     \
        for (int i = 0; i < 4; ++i) {                                         \
            int n = sn + i * 32;                                              \
            float r0 = xq[i].x * kgrev;                                       \
            float r1 = xq[i].y * kgrev;                                       \
            float s0, c0, s1, c1;                                             \
            asm("v_sin_f32 %0, %1" : "=v"(s0) : "v"(r0));                     \
            asm("v_cos_f32 %0, %1" : "=v"(c0) : "v"(r0));                     \
            asm("v_sin_f32 %0, %1" : "=v"(s1) : "v"(r1));                     \
            asm("v_cos_f32 %0, %1" : "=v"(c1) : "v"(r1));                     \
            uint32_t p0, p1;                                                  \
            asm("v_cvt_pk_bf16_f32 %0, %1, %2" : "=v"(p0) : "v"(c0), "v"(s0));\
            asm("v_cvt_pk_bf16_f32 %0, %1, %2" : "=v"(p1) : "v"(c1), "v"(s1));\
            int boff = (n * 128 + sd2 * 8) ^ ((n & 7) << 4);                  \
            uint64_t pk = ((uint64_t)p1 << 32) | (uint64_t)p0;                \
            *(uint64_t*)(abase + boff) = pk;                                  \
        }                                                                     \
    }

    // ---- prologue: chunk (dr=0, g=0) into buffer 0
    LOAD_X(0);
    TRIG_WRITE(1, 0);
    __syncthreads();

    int it = 0;
    for (int dr = 0; dr < 8; ++dr) {
#pragma unroll
        for (int g = 0; g < GRID_G; ++g, ++it) {
            const int cur = it & 1;
            const int c   = g * 8 + dr;             // k-chunk index (k0 = 64*c)
            const char* Ac = (const char*)(As + cur * AS_SH);

            // prefetch next dr-group's x during the last-g chunk
            if (g == GRID_G - 1 && dr < 7) { LOAD_X(dr + 1); }

#pragma unroll
            for (int ks = 0; ks < 2; ++ks) {
                bf16x8 bfr[4], af[4];
#pragma unroll
                for (int nf = 0; nf < 4; ++nf) {
                    int o = wcol * 64 + nf * 16 + (lane & 15);
                    bfr[nf] = *(const bf16x8*)((const char*)Wb +
                              (size_t)o * (KTOT * 2) + c * 128 + ks * 64 + q16);
                }
#pragma unroll
                for (int m = 0; m < 4; ++m) {
                    int rr  = wrow * 64 + m * 16 + (lane & 15);
                    int off = (rr * 128 + ks * 64 + q16) ^ ((rr & 7) << 4);
                    af[m] = *(const bf16x8*)(Ac + off);
                }
#pragma unroll
                for (int m = 0; m < 4; ++m)
#pragma unroll
                    for (int nf = 0; nf < 4; ++nf)
                        acc[m][nf] = __builtin_amdgcn_mfma_f32_16x16x32_bf16(
                            af[m], bfr[nf], acc[m][nf], 0, 0, 0);
            }

            // produce next chunk's A tile into the other buffer
            if (it < NCHUNK - 1) {
                int kgn = (g == GRID_G - 1) ? 1 : (g + 2);
                TRIG_WRITE(kgn, cur ^ 1);
            }
            __syncthreads();
        }
    }

    // ---- epilogue: C/D layout col = lane&15, row = (lane>>4)*4 + reg
#pragma unroll
    for (int nf = 0; nf < 4; ++nf) {
        int ocol = wcol * 64 + nf * 16 + (lane & 15);
        float b = bias[ocol];
#pragma unroll
        for (int m = 0; m < 4; ++m) {
            int rbase = row0 + wrow * 64 + m * 16 + ((lane >> 4) << 2);
#pragma unroll
            for (int r2 = 0; r2 < 4; ++r2) {
                out[(size_t)(rbase + r2) * DIM + ocol] = acc[m][nf][r2] + b;
            }
        }
    }
}

extern "C" void kernel_launch(void* const* d_in, const int* in_sizes, int n_in,
                              void* d_out, int out_size, void* d_ws, size_t ws_size,
                              hipStream_t stream) {
    const float* x    = (const float*)d_in[0];
    const float* W    = (const float*)d_in[1];
    const float* bias = (const float*)d_in[2];
    float* out        = (float*)d_out;
    uint16_t* Wb      = (uint16_t*)d_ws;   // 256*2560*2 = 1.28 MB

    int rows = in_sizes[0] / DIM;          // 65536
    int wthreads = DIM * KTOT / 8;         // 81920

    hipLaunchKernelGGL(wtransform, dim3((wthreads + 255) / 256), dim3(256), 0, stream, W, Wb);
    hipLaunchKernelGGL(fourier_gemm, dim3(rows / BM), dim3(NTHREADS), 0, stream,
                       x, Wb, bias, out);
}

// Round 4
// 234.619 us; speedup vs baseline: 1.5163x; 1.5163x over previous
//
#include <hip/hip_runtime.h>
#include <hip/hip_bf16.h>
#include <stdint.h>

#define DIM 256
#define GRID_G 5
#define KTOT 2560                 // 256 * 5 * 2
#define BM 128
#define BN 256
#define BK 64
#define NTHREADS 256
#define NCHUNK (KTOT / BK)        // 40
#define AS_SH (BM * BK)           // 8192 shorts = 16 KB per buffer

typedef float f32x4 __attribute__((ext_vector_type(4)));
typedef short bf16x8 __attribute__((ext_vector_type(8)));

static __device__ __forceinline__ uint32_t f2bf_bits(float v) {
    uint32_t u = __float_as_uint(v);
    return (u + 0x7FFFu + ((u >> 16) & 1u)) >> 16;
}

// ---- W pre-transform: Wb[o][k] bf16, k = g*512 + 2*d + s ----
// source fourier_weight layout: [s][o][d][g], flat ((s*256+o)*256+d)*5+g
__global__ void wtransform(const float* __restrict__ W, uint16_t* __restrict__ Wb) {
    int t = blockIdx.x * blockDim.x + threadIdx.x;
    if (t >= DIM * KTOT / 8) return;
    int o  = t / (KTOT / 8);            // /320
    int k8 = t - o * (KTOT / 8);
    int k0 = k8 * 8;
    int g  = k0 >> 9;
    int r  = k0 & 511;                  // even
    int d0 = r >> 1;
    union { uint16_t v[8]; uint4 q; } u;
#pragma unroll
    for (int j = 0; j < 8; ++j) {
        int d = d0 + (j >> 1);
        int s = j & 1;
        float w = W[(((s * DIM + o) * DIM + d) * GRID_G) + g];
        u.v[j] = (uint16_t)f2bf_bits(w);
    }
    *(uint4*)((char*)Wb + (size_t)t * 16) = u.q;
}

// ---- fused feature+GEMM: 256 threads, BM=128 x BN=256, wave tile 128x64 ----
// A in LDS (dbuf, XOR-swizzled); B direct global(L2)->reg; 1 barrier/chunk.
__global__ __launch_bounds__(NTHREADS, 2)
void fourier_gemm(const float* __restrict__ x, const uint16_t* __restrict__ Wb,
                  const float* __restrict__ bias, float* __restrict__ out) {
    __shared__ __align__(16) short As[2 * AS_SH];   // 32 KB total

    const int tid  = threadIdx.x;
    const int lane = tid & 63;
    const int wcol = tid >> 6;      // wave index 0..3 = 64-col quarter
    const int row0 = blockIdx.x * BM;
    const int q16  = (lane >> 4) << 4;
    const int l15  = lane & 15;

    f32x4 acc[8][4];
#pragma unroll
    for (int m = 0; m < 8; ++m)
#pragma unroll
        for (int n = 0; n < 4; ++n)
            acc[m][n] = (f32x4){0.f, 0.f, 0.f, 0.f};

    const int sd2 = tid & 15;       // d-pair index within 32-d slab (0..15)
    const int sn  = tid >> 4;       // 0..15 (row base; rows n = sn + i*16)

    float2 xq[8];                   // current dr-group's x slice (16 elements)

#define LOAD_X(dr_)                                                           \
    {                                                                         \
        _Pragma("unroll")                                                     \
        for (int i = 0; i < 8; ++i) {                                         \
            int n = sn + i * 16;                                              \
            xq[i] = *(const float2*)&x[(size_t)(row0 + n) * DIM +             \
                                       (dr_) * 32 + 2 * sd2];                 \
        }                                                                     \
    }

#define TRIG_WRITE(kg1, buf)                                                  \
    {                                                                         \
        float kgrev = (float)(kg1) * 0.15915494309189535f;                    \
        char* abase = (char*)(As + (buf) * AS_SH);                            \
        _Pragma("unroll")                                                     \
        for (int i = 0; i < 8; ++i) {                                         \
            int n = sn + i * 16;                                              \
            float r0 = xq[i].x * kgrev;                                       \
            float r1 = xq[i].y * kgrev;                                       \
            float s0, c0, s1, c1;                                             \
            asm("v_sin_f32 %0, %1" : "=v"(s0) : "v"(r0));                     \
            asm("v_cos_f32 %0, %1" : "=v"(c0) : "v"(r0));                     \
            asm("v_sin_f32 %0, %1" : "=v"(s1) : "v"(r1));                     \
            asm("v_cos_f32 %0, %1" : "=v"(c1) : "v"(r1));                     \
            uint32_t p0, p1;                                                  \
            asm("v_cvt_pk_bf16_f32 %0, %1, %2" : "=v"(p0) : "v"(c0), "v"(s0));\
            asm("v_cvt_pk_bf16_f32 %0, %1, %2" : "=v"(p1) : "v"(c1), "v"(s1));\
            int boff = (n * 128 + sd2 * 8) ^ ((n & 7) << 4);                  \
            uint64_t pk = ((uint64_t)p1 << 32) | (uint64_t)p0;                \
            *(uint64_t*)(abase + boff) = pk;                                  \
        }                                                                     \
    }

    // ---- prologue: chunk (dr=0, g=0) into buffer 0
    LOAD_X(0);
    TRIG_WRITE(1, 0);
    __syncthreads();

    int it = 0;
    for (int dr = 0; dr < 8; ++dr) {
#pragma unroll
        for (int g = 0; g < GRID_G; ++g, ++it) {
            const int cur = it & 1;
            const int c   = g * 8 + dr;             // k-chunk index in Wb
            const char* Ac = (const char*)(As + cur * AS_SH);

            // prefetch next dr-group's x at chunk start (old xq is dead here);
            // latency hides under this chunk's MFMAs
            if (g == GRID_G - 1 && dr < 7) { LOAD_X(dr + 1); }

#pragma unroll
            for (int ks = 0; ks < 2; ++ks) {
                bf16x8 bfr[4], af[8];
#pragma unroll
                for (int nf = 0; nf < 4; ++nf) {
                    int o = wcol * 64 + nf * 16 + l15;
                    bfr[nf] = *(const bf16x8*)((const char*)Wb +
                              (size_t)o * (KTOT * 2) + c * 128 + ks * 64 + q16);
                }
#pragma unroll
                for (int m = 0; m < 8; ++m) {
                    int rr  = m * 16 + l15;
                    int off = (rr * 128 + ks * 64 + q16) ^ ((rr & 7) << 4);
                    af[m] = *(const bf16x8*)(Ac + off);
                }
#pragma unroll
                for (int m = 0; m < 8; ++m)
#pragma unroll
                    for (int nf = 0; nf < 4; ++nf)
                        acc[m][nf] = __builtin_amdgcn_mfma_f32_16x16x32_bf16(
                            af[m], bfr[nf], acc[m][nf], 0, 0, 0);
            }

            // produce next chunk's A tile into the other buffer
            if (it < NCHUNK - 1) {
                int kgn = (g == GRID_G - 1) ? 1 : (g + 2);
                TRIG_WRITE(kgn, cur ^ 1);
            }
            __syncthreads();
        }
    }

    // ---- epilogue: C/D layout col = lane&15, row = (lane>>4)*4 + reg
#pragma unroll
    for (int nf = 0; nf < 4; ++nf) {
        int ocol = wcol * 64 + nf * 16 + l15;
        float b = bias[ocol];
#pragma unroll
        for (int m = 0; m < 8; ++m) {
            int rbase = row0 + m * 16 + ((lane >> 4) << 2);
#pragma unroll
            for (int r2 = 0; r2 < 4; ++r2) {
                out[(size_t)(rbase + r2) * DIM + ocol] = acc[m][nf][r2] + b;
            }
        }
    }
}

extern "C" void kernel_launch(void* const* d_in, const int* in_sizes, int n_in,
                              void* d_out, int out_size, void* d_ws, size_t ws_size,
                              hipStream_t stream) {
    const float* x    = (const float*)d_in[0];
    const float* W    = (const float*)d_in[1];
    const float* bias = (const float*)d_in[2];
    float* out        = (float*)d_out;
    uint16_t* Wb      = (uint16_t*)d_ws;   // 256*2560*2 = 1.28 MB

    int rows = in_sizes[0] / DIM;          // 65536
    int wthreads = DIM * KTOT / 8;         // 81920

    hipLaunchKernelGGL(wtransform, dim3((wthreads + 255) / 256), dim3(256), 0, stream, W, Wb);
    hipLaunchKernelGGL(fourier_gemm, dim3(rows / BM), dim3(NTHREADS), 0, stream,
                       x, Wb, bias, out);
}